// Round 12
// baseline (220.646 us; speedup 1.0000x reference)
//
#include <hip/hip_runtime.h>
#include <stdint.h>

typedef unsigned short u16;
typedef unsigned int u32;
typedef short short8 __attribute__((ext_vector_type(8)));
typedef float f32x4 __attribute__((ext_vector_type(4)));
typedef u32 u32x4 __attribute__((ext_vector_type(4)));

#define T_TOT 32768

__device__ __forceinline__ u16 f2bf(float f) {
  u32 u = __float_as_uint(f);
  return (u16)((u + 0x7fffu + ((u >> 16) & 1u)) >> 16);
}
__device__ __forceinline__ float bf2f(u16 h) {
  return __uint_as_float(((u32)h) << 16);
}
// HW pack: lo=bf16(a), hi=bf16(b). Plain VALU op -> safe as inline asm.
__device__ __forceinline__ u32 cvtpk(float a, float b) {
  u32 r;
  asm("v_cvt_pk_bf16_f32 %0, %1, %2" : "=v"(r) : "v"(a), "v"(b));
  return r;
}

// Async global->LDS 16B copy (direct-to-LDS, no VGPR round trip).
__device__ __forceinline__ void gld_lds16(const void* g, void* l) {
  __builtin_amdgcn_global_load_lds(
      (const __attribute__((address_space(1))) u32*)g,
      (__attribute__((address_space(3))) u32*)l, 16, 0, 0);
}

// P-redistribution double swap (builtin form -> compiler inserts the
// DPP cross-lane wait states; raw-asm version raced).
__device__ __forceinline__ void plswap(u32& a, u32& b) {
#if __has_builtin(__builtin_amdgcn_permlane32_swap) && \
    __has_builtin(__builtin_amdgcn_permlane16_swap)
  typedef u32 u32x2v __attribute__((ext_vector_type(2)));
  u32x2v r = __builtin_amdgcn_permlane32_swap(a, b, false, false);
  u32x2v w = __builtin_amdgcn_permlane16_swap(r[0], r[1], false, false);
  a = w[0]; b = w[1];
#else
  asm volatile(
      "s_nop 2\n\t"
      "v_permlane32_swap_b32 %0, %1\n\t"
      "s_nop 2\n\t"
      "v_permlane16_swap_b32 %0, %1\n\t"
      "s_nop 2"
      : "+v"(a), "+v"(b));
#endif
}

// ---------------------------------------------------------------------------
// Weight convert fp32 -> bf16, row-major [M][K], 16B-chunk XOR swizzle by row.
// ---------------------------------------------------------------------------
__global__ __launch_bounds__(256) void k_wconv(
    const float* __restrict__ fc1, const float* __restrict__ fc2,
    const float* __restrict__ qw, const float* __restrict__ kvw,
    const float* __restrict__ pw, u16* __restrict__ out) {
  int idx = blockIdx.x * 256 + threadIdx.x;  // 32768 chunks total
  const float* src; int K; int rel; u16* dst;
  if (idx < 8192)       { src = fc1; K = 256; rel = idx;         dst = out; }
  else if (idx < 14336) { src = fc2; K = 256; rel = idx - 8192;  dst = out + 65536; }
  else if (idx < 18944) { src = qw;  K = 192; rel = idx - 14336; dst = out + 114688; }
  else if (idx < 28160) { src = kvw; K = 192; rel = idx - 18944; dst = out + 151552; }
  else                  { src = pw;  K = 192; rel = idx - 28160; dst = out + 225280; }
  int nch = K >> 3;
  int m = rel / nch, ch = rel % nch;
  const float* sp = src + (size_t)m * K + ch * 8;
  int pos = (ch & ~7) | ((ch ^ m) & 7);
  u16* dp = dst + (size_t)m * K + pos * 8;
  ushort4 u0, u1;
  u0.x = f2bf(sp[0]); u0.y = f2bf(sp[1]); u0.z = f2bf(sp[2]); u0.w = f2bf(sp[3]);
  u1.x = f2bf(sp[4]); u1.y = f2bf(sp[5]); u1.z = f2bf(sp[6]); u1.w = f2bf(sp[7]);
  *(ushort4*)(dp) = u0;
  *(ushort4*)(dp + 4) = u1;
}

// ---------------------------------------------------------------------------
// Transpose: src fp32 [C][32768] -> dst bf16 [32768][C] token-major swizzled.
// ---------------------------------------------------------------------------
template<int C>
__global__ __launch_bounds__(256) void k_transpose(const float* __restrict__ src,
                                                   u16* __restrict__ dst) {
  __shared__ u16 sT[64][72];
  int c0 = blockIdx.x * 64, t0 = blockIdx.y * 64;
  int tid = threadIdx.x;
  for (int i = tid; i < 1024; i += 256) {
    int row = i >> 4;
    int tb  = (i & 15) * 4;
    const float* sp = src + (size_t)(c0 + row) * T_TOT + t0 + tb;
    float4 v = *(const float4*)sp;
    ushort4 u;
    u.x = f2bf(v.x); u.y = f2bf(v.y); u.z = f2bf(v.z); u.w = f2bf(v.w);
    *(ushort4*)(&sT[row][tb]) = u;
  }
  __syncthreads();
  int tl = tid & 63;
  int jb = tid >> 6;
  for (int p = 0; p < 2; ++p) {
    int j = jb + 4 * p;
    int t = t0 + tl;
    u16 e[8];
#pragma unroll
    for (int e8 = 0; e8 < 8; ++e8) e[e8] = sT[j * 8 + e8][tl];
    int pos = (c0 >> 3) + (j ^ (t & 7));
    uint4 o;
    o.x = (u32)e[0] | ((u32)e[1] << 16);
    o.y = (u32)e[2] | ((u32)e[3] << 16);
    o.z = (u32)e[4] | ((u32)e[5] << 16);
    o.w = (u32)e[6] | ((u32)e[7] << 16);
    *(uint4*)(dst + (size_t)t * C + pos * 8) = o;
  }
}

// ---------------------------------------------------------------------------
// Barrier-free register GEMM: out(M x 32768) = W(MxK) * Bt^T.
// Shallow K (<=256) regime: W fragments preloaded to registers (W tile is
// L2-resident across all t-blocks); B fragments read directly from global in
// stored swizzled order (pos = (l&~7)|((l^c)&7), since row&7 == c&7 for all
// tile bases). No LDS, no barriers, no staging drain -- the loop is pure
// {4 x 16B global load + 8 MFMA}. 64m x 128t, 4 waves (2x2).
// ---------------------------------------------------------------------------
enum { EPI_FC1 = 0, EPI_FC2 = 1, EPI_Q = 2, EPI_KV = 3 };

template<int M, int K, int EPI>
__global__ __launch_bounds__(256) void k_gemm(const u16* __restrict__ W,
    const u16* __restrict__ B, const float* __restrict__ bias,
    const float* __restrict__ ls,
    u16* __restrict__ out, u16* __restrict__ out2) {
  constexpr int NKC = K / 32;
  int tid = threadIdx.x;
  int lane = tid & 63, wid = tid >> 6;
  int g = lane >> 4, c = lane & 15;
  int wm = wid >> 1, wt = wid & 1;
  int t0 = blockIdx.x * 128, m0 = blockIdx.y * 64;

  // preload all W fragments into registers
  short8 af[2][NKC];
#pragma unroll
  for (int mt = 0; mt < 2; ++mt) {
    const u16* wr = W + (size_t)(m0 + wm * 32 + mt * 16 + c) * K;
#pragma unroll
    for (int kc = 0; kc < NKC; ++kc) {
      int l = kc * 4 + g;
      int pos = (l & ~7) | ((l ^ c) & 7);
      af[mt][kc] = *(const short8*)(wr + pos * 8);
    }
  }
  const u16* bt0 = B + (size_t)(t0 + wt * 64 + c) * K;

  f32x4 acc[2][4];
#pragma unroll
  for (int i = 0; i < 2; ++i)
#pragma unroll
    for (int j = 0; j < 4; ++j) acc[i][j] = f32x4{0.f, 0.f, 0.f, 0.f};

#pragma unroll 2
  for (int kc = 0; kc < NKC; ++kc) {
    int l = kc * 4 + g;
    int pos8 = ((l & ~7) | ((l ^ c) & 7)) * 8;
    short8 bfr[4];
#pragma unroll
    for (int tt = 0; tt < 4; ++tt)
      bfr[tt] = *(const short8*)(bt0 + (size_t)(tt * 16) * K + pos8);
#pragma unroll
    for (int mt = 0; mt < 2; ++mt)
#pragma unroll
      for (int tt = 0; tt < 4; ++tt)
        acc[mt][tt] = __builtin_amdgcn_mfma_f32_16x16x32_bf16(
            af[mt][kc], bfr[tt], acc[mt][tt], 0, 0, 0);
  }

  // bias into registers
  float vv[2][4][4];
#pragma unroll
  for (int mt = 0; mt < 2; ++mt) {
    int m_base = m0 + wm * 32 + mt * 16 + 4 * g;
    float br[4];
    if constexpr (EPI == EPI_KV) {
      if (m_base < 192) { br[0] = br[1] = br[2] = br[3] = 0.f; }
      else {
        float4 b4 = *(const float4*)(bias + (m_base - 192));
        br[0] = b4.x; br[1] = b4.y; br[2] = b4.z; br[3] = b4.w;
      }
    } else {
      float4 b4 = *(const float4*)(bias + m_base);
      br[0] = b4.x; br[1] = b4.y; br[2] = b4.z; br[3] = b4.w;
    }
#pragma unroll
    for (int tt = 0; tt < 4; ++tt)
#pragma unroll
      for (int r = 0; r < 4; ++r) vv[mt][tt][r] = acc[mt][tt][r] + br[r];
  }

  // fold cosine normalization (Q also folds exp(min(ls,ln100))*log2e)
  if constexpr (EPI == EPI_Q || EPI == EPI_KV) {
    if (EPI == EPI_Q || m0 < 192) {
      float sc = 1.0f;
      if constexpr (EPI == EPI_Q) {
        int headq = (m0 + wm * 32) >> 5;
        sc = __expf(fminf(ls[headq], 4.6051701859880914f)) * 1.4426950408889634f;
      }
#pragma unroll
      for (int tt = 0; tt < 4; ++tt) {
        float ss = 0.f;
#pragma unroll
        for (int mt = 0; mt < 2; ++mt)
#pragma unroll
          for (int r = 0; r < 4; ++r) ss += vv[mt][tt][r] * vv[mt][tt][r];
        ss += __shfl_xor(ss, 16);
        ss += __shfl_xor(ss, 32);
        float rn = sc / fmaxf(sqrtf(ss), 1e-12f);
#pragma unroll
        for (int mt = 0; mt < 2; ++mt)
#pragma unroll
          for (int r = 0; r < 4; ++r) vv[mt][tt][r] *= rn;
      }
    }
  }

#pragma unroll
  for (int mt = 0; mt < 2; ++mt) {
    int m_base = m0 + wm * 32 + mt * 16 + 4 * g;
#pragma unroll
    for (int tt = 0; tt < 4; ++tt) {
      int t = t0 + wt * 64 + tt * 16 + c;
      float v[4];
#pragma unroll
      for (int r = 0; r < 4; ++r) v[r] = vv[mt][tt][r];
      if constexpr (EPI == EPI_FC1) {
#pragma unroll
        for (int r = 0; r < 4; ++r)
          v[r] = 0.5f * v[r] * (1.0f + erff(v[r] * 0.70710678118654752f));
      }
      if constexpr (EPI == EPI_FC1 || EPI == EPI_FC2) {
        ushort4 u;
        u.x = f2bf(v[0]); u.y = f2bf(v[1]); u.z = f2bf(v[2]); u.w = f2bf(v[3]);
        int pos = (m_base >> 3) ^ (t & 7);
        *(ushort4*)(out + (size_t)t * M + (pos << 3) + (m_base & 7)) = u;
      } else {
        int z = t >> 10, y = (t >> 5) & 31, xx = t & 31;
        int win = ((z >> 3) << 4) + ((y >> 3) << 2) + (xx >> 3);
        int n = ((z & 7) << 6) + ((y & 7) << 3) + (xx & 7);
        if (EPI == EPI_Q) {
          int head = m_base >> 5, dim = m_base & 31;
          ushort4 u;
          u.x = f2bf(v[0]); u.y = f2bf(v[1]); u.z = f2bf(v[2]); u.w = f2bf(v[3]);
          *(ushort4*)(out + ((size_t)(win * 6 + head) * 512 + n) * 32 + dim) = u;
        } else if (m_base < 192) {  // K: padded [512][36] layout
          int head = m_base >> 5, dim = m_base & 31;
          ushort4 u;
          u.x = f2bf(v[0]); u.y = f2bf(v[1]); u.z = f2bf(v[2]); u.w = f2bf(v[3]);
          *(ushort4*)(out + ((size_t)(win * 6 + head) * 512 + n) * 36 + dim) = u;
        } else {
          int vb = m_base - 192;
          int head = vb >> 5, dimb = vb & 31;
#pragma unroll
          for (int r = 0; r < 4; ++r) {
            int dimr = dimb + r;
            out2[((size_t)(win * 6 + head) * 32 + dimr) * 512 +
                 (((n >> 3) ^ (dimr & 7)) << 3) + (n & 7)] = f2bf(v[r]);
          }
        }
      }
    }
  }
}

// ---------------------------------------------------------------------------
// Windowed cosine attention. Grid (zq*6+head = 12, win = 64) = 768 blocks
// (3/CU co-resident; LDS 36.9KB). K pre-normalized padded [512][36] ->
// linear global_load_lds staging. Q pre-normalized+scaled -> raw loads.
// V from global (L1/L2-resident, 8x reuse). Streaming softmax, ones-MFMA
// row sums, cvtpk+permlane P, unroll-4 + setprio around MFMA clusters.
// ---------------------------------------------------------------------------
__global__ __launch_bounds__(256) void k_attn(const u16* __restrict__ Qw,
    const u16* __restrict__ Kw, const u16* __restrict__ Vw,
    u16* __restrict__ Amat) {
  __shared__ u16 Kn[512 * 36];
  int tid = threadIdx.x, lane = tid & 63, wid = tid >> 6;
  int g = lane >> 4, c = lane & 15;
  int zq = blockIdx.x / 6, head = blockIdx.x % 6, win = blockIdx.y;
  const u16* Kg = Kw + (size_t)(win * 6 + head) * 18432;
  const u16* Vg = Vw + (size_t)(win * 6 + head) * 16384;
  const u16* Qg = Qw + (size_t)(win * 6 + head) * 16384;
  for (int i = tid; i < 2304; i += 256)
    gld_lds16(Kg + (size_t)i * 8, Kn + (size_t)i * 8);
  __syncthreads();

  int wz = win >> 4, wy = (win >> 2) & 3, wx = win & 3;
  u32x4 onepk;
  onepk[0] = 0x3F803F80u; onepk[1] = 0x3F803F80u;
  onepk[2] = 0x3F803F80u; onepk[3] = 0x3F803F80u;
  short8 ONES = __builtin_bit_cast(short8, onepk);

  for (int qp = 0; qp < 2; ++qp) {
    int q0A = zq * 256 + wid * 64 + qp * 32;
    int q0B = q0A + 16;
    short8 qfA = *(const short8*)(Qg + (size_t)(q0A + c) * 32 + g * 8);
    short8 qfB = *(const short8*)(Qg + (size_t)(q0B + c) * 32 + g * 8);

    f32x4 o0A = {0.f, 0.f, 0.f, 0.f}, o1A = {0.f, 0.f, 0.f, 0.f};
    f32x4 o2A = {0.f, 0.f, 0.f, 0.f};
    f32x4 o0B = {0.f, 0.f, 0.f, 0.f}, o1B = {0.f, 0.f, 0.f, 0.f};
    f32x4 o2B = {0.f, 0.f, 0.f, 0.f};
#pragma unroll 4
    for (int cc = 0; cc < 16; ++cc) {
      short8 kf0 = *(const short8*)(Kn + (size_t)(cc * 32 + c) * 36 + g * 8);
      short8 kf1 = *(const short8*)(Kn + (size_t)(cc * 32 + 16 + c) * 36 + g * 8);
      int chpos = ((cc * 4 + g) ^ (c & 7)) << 3;
      short8 vf0 = *(const short8*)(Vg + (size_t)c * 512 + chpos);
      short8 vf1 = *(const short8*)(Vg + (size_t)(16 + c) * 512 + chpos);
      __builtin_amdgcn_s_setprio(1);
      f32x4 s0A = __builtin_amdgcn_mfma_f32_16x16x32_bf16(
          kf0, qfA, f32x4{0.f, 0.f, 0.f, 0.f}, 0, 0, 0);
      f32x4 s1A = __builtin_amdgcn_mfma_f32_16x16x32_bf16(
          kf1, qfA, f32x4{0.f, 0.f, 0.f, 0.f}, 0, 0, 0);
      f32x4 s0B = __builtin_amdgcn_mfma_f32_16x16x32_bf16(
          kf0, qfB, f32x4{0.f, 0.f, 0.f, 0.f}, 0, 0, 0);
      f32x4 s1B = __builtin_amdgcn_mfma_f32_16x16x32_bf16(
          kf1, qfB, f32x4{0.f, 0.f, 0.f, 0.f}, 0, 0, 0);
      __builtin_amdgcn_s_setprio(0);
      f32x4 p0A, p1A, p0B, p1B;
#pragma unroll
      for (int r = 0; r < 4; ++r) {
        p0A[r] = __builtin_amdgcn_exp2f(s0A[r]);
        p1A[r] = __builtin_amdgcn_exp2f(s1A[r]);
        p0B[r] = __builtin_amdgcn_exp2f(s0B[r]);
        p1B[r] = __builtin_amdgcn_exp2f(s1B[r]);
      }
      u32 waA = cvtpk(p0A[0], p0A[1]), wbA = cvtpk(p0A[2], p0A[3]);
      u32 wcA = cvtpk(p1A[0], p1A[1]), wdA = cvtpk(p1A[2], p1A[3]);
      plswap(waA, wcA);
      plswap(wbA, wdA);
      u32 waB = cvtpk(p0B[0], p0B[1]), wbB = cvtpk(p0B[2], p0B[3]);
      u32 wcB = cvtpk(p1B[0], p1B[1]), wdB = cvtpk(p1B[2], p1B[3]);
      plswap(waB, wcB);
      plswap(wbB, wdB);
      u32x4 pwA, pwB;
      pwA[0] = waA; pwA[1] = wbA; pwA[2] = wcA; pwA[3] = wdA;
      pwB[0] = waB; pwB[1] = wbB; pwB[2] = wcB; pwB[3] = wdB;
      short8 pfA = __builtin_bit_cast(short8, pwA);
      short8 pfB = __builtin_bit_cast(short8, pwB);
      __builtin_amdgcn_s_setprio(1);
      o0A = __builtin_amdgcn_mfma_f32_16x16x32_bf16(pfA, vf0, o0A, 0, 0, 0);
      o1A = __builtin_amdgcn_mfma_f32_16x16x32_bf16(pfA, vf1, o1A, 0, 0, 0);
      o2A = __builtin_amdgcn_mfma_f32_16x16x32_bf16(pfA, ONES, o2A, 0, 0, 0);
      o0B = __builtin_amdgcn_mfma_f32_16x16x32_bf16(pfB, vf0, o0B, 0, 0, 0);
      o1B = __builtin_amdgcn_mfma_f32_16x16x32_bf16(pfB, vf1, o1B, 0, 0, 0);
      o2B = __builtin_amdgcn_mfma_f32_16x16x32_bf16(pfB, ONES, o2B, 0, 0, 0);
      __builtin_amdgcn_s_setprio(0);
    }

#pragma unroll
    for (int half = 0; half < 2; ++half) {
      f32x4 oo0 = half ? o0B : o0A;
      f32x4 oo1 = half ? o1B : o1A;
      f32x4 osum = half ? o2B : o2A;
      int q0 = half ? q0B : q0A;
      int cg0 = head * 32 + c;
      int cg1 = cg0 + 16;
#pragma unroll
      for (int r = 0; r < 4; ++r) {
        float rs = 1.0f / osum[r];
        int n = q0 + 4 * g + r;
        int dz = n >> 6, dy = (n >> 3) & 7, dx = n & 7;
        int t = (wz * 8 + dz) * 1024 + (wy * 8 + dy) * 32 + wx * 8 + dx;
        Amat[(size_t)t * 192 + (((cg0 >> 3) ^ (t & 7)) << 3) + (cg0 & 7)] =
            f2bf(oo0[r] * rs);
        Amat[(size_t)t * 192 + (((cg1 >> 3) ^ (t & 7)) << 3) + (cg1 & 7)] =
            f2bf(oo1[r] * rs);
      }
    }
  }
}

// ---------------------------------------------------------------------------
// Fused proj-GEMM + residual + LayerNorm, register-GEMM form. Tile: all 192
// channels x 64 tokens, 4 waves x 48 rows. W/Amat fragments from global
// (L2-hot); LDS only for the 2KB cross-wave LN reduction.
// ---------------------------------------------------------------------------
__global__ __launch_bounds__(256) void k_proj_ln(const u16* __restrict__ W,
    const u16* __restrict__ B, const float* __restrict__ bias,
    const float* __restrict__ x, const float* __restrict__ gg,
    const float* __restrict__ bb, float* __restrict__ out) {
  __shared__ float red[2][4][64];
  int tid = threadIdx.x;
  int lane = tid & 63, wid = tid >> 6;
  int g = lane >> 4, c = lane & 15;
  int t0 = blockIdx.x * 64;

  short8 af[3][6];
#pragma unroll
  for (int mt = 0; mt < 3; ++mt) {
    const u16* wr = W + (size_t)(wid * 48 + mt * 16 + c) * 192;
#pragma unroll
    for (int kc = 0; kc < 6; ++kc) {
      int l = kc * 4 + g;
      int pos = (l & ~7) | ((l ^ c) & 7);
      af[mt][kc] = *(const short8*)(wr + pos * 8);
    }
  }
  const u16* bt0 = B + (size_t)(t0 + c) * 192;

  f32x4 acc[3][4];
#pragma unroll
  for (int i = 0; i < 3; ++i)
#pragma unroll
    for (int j = 0; j < 4; ++j) acc[i][j] = f32x4{0.f, 0.f, 0.f, 0.f};

#pragma unroll 2
  for (int kc = 0; kc < 6; ++kc) {
    int l = kc * 4 + g;
    int pos8 = ((l & ~7) | ((l ^ c) & 7)) * 8;
    short8 bfr[4];
#pragma unroll
    for (int tt = 0; tt < 4; ++tt)
      bfr[tt] = *(const short8*)(bt0 + (size_t)(tt * 16) * 192 + pos8);
#pragma unroll
    for (int mt = 0; mt < 3; ++mt)
#pragma unroll
      for (int tt = 0; tt < 4; ++tt)
        acc[mt][tt] = __builtin_amdgcn_mfma_f32_16x16x32_bf16(
            af[mt][kc], bfr[tt], acc[mt][tt], 0, 0, 0);
  }

  float br[3][4];
#pragma unroll
  for (int mt = 0; mt < 3; ++mt) {
    float4 b4 = *(const float4*)(bias + wid * 48 + mt * 16 + 4 * g);
    br[mt][0] = b4.x; br[mt][1] = b4.y; br[mt][2] = b4.z; br[mt][3] = b4.w;
  }
  float s1[4], s2[4];
#pragma unroll
  for (int tt = 0; tt < 4; ++tt) {
    s1[tt] = 0.f; s2[tt] = 0.f;
#pragma unroll
    for (int mt = 0; mt < 3; ++mt)
#pragma unroll
      for (int r = 0; r < 4; ++r) {
        float v = acc[mt][tt][r] + br[mt][r];
        s1[tt] += v;
        s2[tt] += v * v;
      }
    s1[tt] += __shfl_xor(s1[tt], 16); s1[tt] += __shfl_xor(s1[tt], 32);
    s2[tt] += __shfl_xor(s2[tt], 16); s2[tt] += __shfl_xor(s2[tt], 32);
  }
  if (lane < 16) {
#pragma unroll
    for (int tt = 0; tt < 4; ++tt) {
      red[0][wid][tt * 16 + lane] = s1[tt];
      red[1][wid][tt * 16 + lane] = s2[tt];
    }
  }
  __syncthreads();
  float mean[4], rstd[4];
#pragma unroll
  for (int tt = 0; tt < 4; ++tt) {
    int tl = tt * 16 + c;
    float S1 = (red[0][0][tl] + red[0][1][tl]) + (red[0][2][tl] + red[0][3][tl]);
    float S2 = (red[1][0][tl] + red[1][1][tl]) + (red[1][2][tl] + red[1][3][tl]);
    float m = S1 * (1.0f / 192.0f);
    float var = S2 * (1.0f / 192.0f) - m * m;
    mean[tt] = m;
    rstd[tt] = rsqrtf(var + 1e-5f);
  }
#pragma unroll
  for (int mt = 0; mt < 3; ++mt) {
    int m_base = wid * 48 + mt * 16 + 4 * g;
#pragma unroll
    for (int r = 0; r < 4; ++r) {
      int ch = m_base + r;
      float ga = gg[ch], ba = bb[ch];
      const float* xp = x + (size_t)ch * T_TOT + t0;
      float* op = out + (size_t)ch * T_TOT + t0;
#pragma unroll
      for (int tt = 0; tt < 4; ++tt) {
        int tl = tt * 16 + c;
        float v = acc[mt][tt][r] + br[mt][r];
        op[tl] = xp[tl] + (v - mean[tt]) * rstd[tt] * ga + ba;
      }
    }
  }
}

// ---------------------------------------------------------------------------
extern "C" void kernel_launch(void* const* d_in, const int* in_sizes, int n_in,
                              void* d_out, int out_size, void* d_ws, size_t ws_size,
                              hipStream_t stream) {
  const float* x      = (const float*)d_in[0];
  const float* prev   = (const float*)d_in[1];
  const float* fc1_w  = (const float*)d_in[2];
  const float* fc1_b  = (const float*)d_in[3];
  const float* fc2_w  = (const float*)d_in[4];
  const float* fc2_b  = (const float*)d_in[5];
  const float* q_w    = (const float*)d_in[6];
  const float* q_b    = (const float*)d_in[7];
  const float* kv_w   = (const float*)d_in[8];
  const float* v_b    = (const float*)d_in[9];
  const float* proj_w = (const float*)d_in[10];
  const float* proj_b = (const float*)d_in[11];
  const float* lsc    = (const float*)d_in[12];
  const float* ln_g   = (const float*)d_in[13];
  const float* ln_b   = (const float*)d_in[14];
  float* out = (float*)d_out;
  char* ws = (char*)d_ws;

  u16* Pt   = (u16*)(ws + 0);          // [32768][256] bf16 swz   (16 MiB)
  u16* Y1t  = (u16*)(ws + 16777216);   // [32768][256]            (16 MiB)
  u16* Zt   = (u16*)(ws + 33554432);   // [32768][192]            (12 MiB)
  u16* Xt   = (u16*)(ws + 46137344);   // [32768][192] (dead after q-GEMM)
  u16* Kwin = (u16*)(ws + 46137344);   // [384][512][36] padded (aliases Xt)
  u16* Vwin = (u16*)(ws + 60293120);   // [64][6][32][512] swz    (12 MiB)
  u16* Wbf  = (u16*)(ws + 72876032);   // 262144 bf16 weights
  u16* Qwin = Pt;    // alias: Pt dead after fc1
  u16* Amat = Y1t;   // alias: Y1t dead after fc2

  k_wconv<<<128, 256, 0, stream>>>(fc1_w, fc2_w, q_w, kv_w, proj_w, Wbf);
  k_transpose<256><<<dim3(4, 512), 256, 0, stream>>>(prev, Pt);
  k_transpose<192><<<dim3(3, 512), 256, 0, stream>>>(x, Xt);
  k_gemm<256, 256, EPI_FC1><<<dim3(256, 4), 256, 0, stream>>>(Wbf, Pt, fc1_b, nullptr, Y1t, nullptr);
  k_gemm<192, 256, EPI_FC2><<<dim3(256, 3), 256, 0, stream>>>(Wbf + 65536, Y1t, fc2_b, nullptr, Zt, nullptr);
  k_gemm<192, 192, EPI_Q><<<dim3(256, 3), 256, 0, stream>>>(Wbf + 114688, Xt, q_b, lsc, Qwin, nullptr);
  k_gemm<384, 192, EPI_KV><<<dim3(256, 6), 256, 0, stream>>>(Wbf + 151552, Zt, v_b, nullptr, Kwin, Vwin);
  k_attn<<<dim3(12, 64), 256, 0, stream>>>(Qwin, Kwin, Vwin, Amat);
  k_proj_ln<<<512, 256, 0, stream>>>(Wbf + 225280, Amat, proj_b, x, ln_g, ln_b, out);
}

// Round 13
// 127.320 us; speedup vs baseline: 1.7330x; 1.7330x over previous
//
#include <hip/hip_runtime.h>
#include <stdint.h>

typedef unsigned short u16;
typedef unsigned int u32;
typedef short short8 __attribute__((ext_vector_type(8)));
typedef float f32x4 __attribute__((ext_vector_type(4)));
typedef u32 u32x4 __attribute__((ext_vector_type(4)));

#define T_TOT 32768

__device__ __forceinline__ u16 f2bf(float f) {
  u32 u = __float_as_uint(f);
  return (u16)((u + 0x7fffu + ((u >> 16) & 1u)) >> 16);
}
__device__ __forceinline__ float bf2f(u16 h) {
  return __uint_as_float(((u32)h) << 16);
}
// HW pack: lo=bf16(a), hi=bf16(b). Plain VALU op -> safe as inline asm.
__device__ __forceinline__ u32 cvtpk(float a, float b) {
  u32 r;
  asm("v_cvt_pk_bf16_f32 %0, %1, %2" : "=v"(r) : "v"(a), "v"(b));
  return r;
}

// Async global->LDS 16B copy (direct-to-LDS, no VGPR round trip).
__device__ __forceinline__ void gld_lds16(const void* g, void* l) {
  __builtin_amdgcn_global_load_lds(
      (const __attribute__((address_space(1))) u32*)g,
      (__attribute__((address_space(3))) u32*)l, 16, 0, 0);
}

// P-redistribution double swap (builtin form -> compiler inserts the
// DPP cross-lane wait states; raw-asm version raced).
__device__ __forceinline__ void plswap(u32& a, u32& b) {
#if __has_builtin(__builtin_amdgcn_permlane32_swap) && \
    __has_builtin(__builtin_amdgcn_permlane16_swap)
  typedef u32 u32x2v __attribute__((ext_vector_type(2)));
  u32x2v r = __builtin_amdgcn_permlane32_swap(a, b, false, false);
  u32x2v w = __builtin_amdgcn_permlane16_swap(r[0], r[1], false, false);
  a = w[0]; b = w[1];
#else
  asm volatile(
      "s_nop 2\n\t"
      "v_permlane32_swap_b32 %0, %1\n\t"
      "s_nop 2\n\t"
      "v_permlane16_swap_b32 %0, %1\n\t"
      "s_nop 2"
      : "+v"(a), "+v"(b));
#endif
}

// ---------------------------------------------------------------------------
// Weight convert fp32 -> bf16, row-major [M][K], 16B-chunk XOR swizzle by row.
// ---------------------------------------------------------------------------
__global__ __launch_bounds__(256) void k_wconv(
    const float* __restrict__ fc1, const float* __restrict__ fc2,
    const float* __restrict__ qw, const float* __restrict__ kvw,
    const float* __restrict__ pw, u16* __restrict__ out) {
  int idx = blockIdx.x * 256 + threadIdx.x;  // 32768 chunks total
  const float* src; int K; int rel; u16* dst;
  if (idx < 8192)       { src = fc1; K = 256; rel = idx;         dst = out; }
  else if (idx < 14336) { src = fc2; K = 256; rel = idx - 8192;  dst = out + 65536; }
  else if (idx < 18944) { src = qw;  K = 192; rel = idx - 14336; dst = out + 114688; }
  else if (idx < 28160) { src = kvw; K = 192; rel = idx - 18944; dst = out + 151552; }
  else                  { src = pw;  K = 192; rel = idx - 28160; dst = out + 225280; }
  int nch = K >> 3;
  int m = rel / nch, ch = rel % nch;
  const float* sp = src + (size_t)m * K + ch * 8;
  int pos = (ch & ~7) | ((ch ^ m) & 7);
  u16* dp = dst + (size_t)m * K + pos * 8;
  ushort4 u0, u1;
  u0.x = f2bf(sp[0]); u0.y = f2bf(sp[1]); u0.z = f2bf(sp[2]); u0.w = f2bf(sp[3]);
  u1.x = f2bf(sp[4]); u1.y = f2bf(sp[5]); u1.z = f2bf(sp[6]); u1.w = f2bf(sp[7]);
  *(ushort4*)(dp) = u0;
  *(ushort4*)(dp + 4) = u1;
}

// ---------------------------------------------------------------------------
// Transpose: src fp32 [C][32768] -> dst bf16 [32768][C] token-major swizzled.
// ---------------------------------------------------------------------------
template<int C>
__global__ __launch_bounds__(256) void k_transpose(const float* __restrict__ src,
                                                   u16* __restrict__ dst) {
  __shared__ u16 sT[64][72];
  int c0 = blockIdx.x * 64, t0 = blockIdx.y * 64;
  int tid = threadIdx.x;
  for (int i = tid; i < 1024; i += 256) {
    int row = i >> 4;
    int tb  = (i & 15) * 4;
    const float* sp = src + (size_t)(c0 + row) * T_TOT + t0 + tb;
    float4 v = *(const float4*)sp;
    ushort4 u;
    u.x = f2bf(v.x); u.y = f2bf(v.y); u.z = f2bf(v.z); u.w = f2bf(v.w);
    *(ushort4*)(&sT[row][tb]) = u;
  }
  __syncthreads();
  int tl = tid & 63;
  int jb = tid >> 6;
  for (int p = 0; p < 2; ++p) {
    int j = jb + 4 * p;
    int t = t0 + tl;
    u16 e[8];
#pragma unroll
    for (int e8 = 0; e8 < 8; ++e8) e[e8] = sT[j * 8 + e8][tl];
    int pos = (c0 >> 3) + (j ^ (t & 7));
    uint4 o;
    o.x = (u32)e[0] | ((u32)e[1] << 16);
    o.y = (u32)e[2] | ((u32)e[3] << 16);
    o.z = (u32)e[4] | ((u32)e[5] << 16);
    o.w = (u32)e[6] | ((u32)e[7] << 16);
    *(uint4*)(dst + (size_t)t * C + pos * 8) = o;
  }
}

// ---------------------------------------------------------------------------
// Hybrid GEMM: out(M x 32768) = W(MxK) * Bt^T. W fragments preloaded to
// registers (one-time uncoalesced read of the L2-resident W tile, amortized
// over the K loop); B staged to LDS via coalesced global_load_lds (R12
// showed direct-from-global B-fragments overfetch 4x at stride-K).
// 64m x 128t, 4 waves (2x2); LDS 16KB (B only).
// ---------------------------------------------------------------------------
enum { EPI_FC1 = 0, EPI_FC2 = 1, EPI_Q = 2, EPI_KV = 3 };

template<int M, int K, int EPI>
__global__ __launch_bounds__(256) void k_gemm(const u16* __restrict__ W,
    const u16* __restrict__ B, const float* __restrict__ bias,
    const float* __restrict__ ls,
    u16* __restrict__ out, u16* __restrict__ out2) {
  __shared__ u16 lB[128 * 64];
  constexpr int NKC = K / 32;
  int tid = threadIdx.x;
  int lane = tid & 63, wid = tid >> 6;
  int g = lane >> 4, c = lane & 15;
  int wm = wid >> 1, wt = wid & 1;
  int t0 = blockIdx.x * 128, m0 = blockIdx.y * 64;

  // preload all W fragments into registers (W tile is L2-resident)
  short8 af[2][NKC];
#pragma unroll
  for (int mt = 0; mt < 2; ++mt) {
    const u16* wr = W + (size_t)(m0 + wm * 32 + mt * 16 + c) * K;
#pragma unroll
    for (int kc = 0; kc < NKC; ++kc) {
      int l = kc * 4 + g;
      int pos = (l & ~7) | ((l ^ c) & 7);
      af[mt][kc] = *(const short8*)(wr + pos * 8);
    }
  }

  f32x4 acc[2][4];
#pragma unroll
  for (int i = 0; i < 2; ++i)
#pragma unroll
    for (int j = 0; j < 4; ++j) acc[i][j] = f32x4{0.f, 0.f, 0.f, 0.f};

  for (int s = 0; s < K / 64; ++s) {
    __syncthreads();
#pragma unroll
    for (int i0 = 0; i0 < 1024; i0 += 256) {
      int i = i0 + tid;
      int r = i >> 3, ch = i & 7;
      gld_lds16(B + (size_t)(t0 + r) * K + s * 64 + ch * 8,
                lB + (size_t)(i & ~63) * 8);
    }
    __syncthreads();
#pragma unroll
    for (int kc2 = 0; kc2 < 2; ++kc2) {
      short8 bfr[4];
#pragma unroll
      for (int tt = 0; tt < 4; ++tt) {
        int r = wt * 64 + tt * 16 + c;
        bfr[tt] = *(const short8*)(lB + r * 64 + (((kc2 * 4 + g) ^ (r & 7)) << 3));
      }
#pragma unroll
      for (int mt = 0; mt < 2; ++mt)
#pragma unroll
        for (int tt = 0; tt < 4; ++tt)
          acc[mt][tt] = __builtin_amdgcn_mfma_f32_16x16x32_bf16(
              af[mt][s * 2 + kc2], bfr[tt], acc[mt][tt], 0, 0, 0);
    }
  }

  // bias into registers
  float vv[2][4][4];
#pragma unroll
  for (int mt = 0; mt < 2; ++mt) {
    int m_base = m0 + wm * 32 + mt * 16 + 4 * g;
    float br[4];
    if constexpr (EPI == EPI_KV) {
      if (m_base < 192) { br[0] = br[1] = br[2] = br[3] = 0.f; }
      else {
        float4 b4 = *(const float4*)(bias + (m_base - 192));
        br[0] = b4.x; br[1] = b4.y; br[2] = b4.z; br[3] = b4.w;
      }
    } else {
      float4 b4 = *(const float4*)(bias + m_base);
      br[0] = b4.x; br[1] = b4.y; br[2] = b4.z; br[3] = b4.w;
    }
#pragma unroll
    for (int tt = 0; tt < 4; ++tt)
#pragma unroll
      for (int r = 0; r < 4; ++r) vv[mt][tt][r] = acc[mt][tt][r] + br[r];
  }

  // fold cosine normalization (Q also folds exp(min(ls,ln100))*log2e)
  if constexpr (EPI == EPI_Q || EPI == EPI_KV) {
    if (EPI == EPI_Q || m0 < 192) {
      float sc = 1.0f;
      if constexpr (EPI == EPI_Q) {
        int headq = (m0 + wm * 32) >> 5;
        sc = __expf(fminf(ls[headq], 4.6051701859880914f)) * 1.4426950408889634f;
      }
#pragma unroll
      for (int tt = 0; tt < 4; ++tt) {
        float ss = 0.f;
#pragma unroll
        for (int mt = 0; mt < 2; ++mt)
#pragma unroll
          for (int r = 0; r < 4; ++r) ss += vv[mt][tt][r] * vv[mt][tt][r];
        ss += __shfl_xor(ss, 16);
        ss += __shfl_xor(ss, 32);
        float rn = sc / fmaxf(sqrtf(ss), 1e-12f);
#pragma unroll
        for (int mt = 0; mt < 2; ++mt)
#pragma unroll
          for (int r = 0; r < 4; ++r) vv[mt][tt][r] *= rn;
      }
    }
  }

#pragma unroll
  for (int mt = 0; mt < 2; ++mt) {
    int m_base = m0 + wm * 32 + mt * 16 + 4 * g;
#pragma unroll
    for (int tt = 0; tt < 4; ++tt) {
      int t = t0 + wt * 64 + tt * 16 + c;
      float v[4];
#pragma unroll
      for (int r = 0; r < 4; ++r) v[r] = vv[mt][tt][r];
      if constexpr (EPI == EPI_FC1) {
#pragma unroll
        for (int r = 0; r < 4; ++r)
          v[r] = 0.5f * v[r] * (1.0f + erff(v[r] * 0.70710678118654752f));
      }
      if constexpr (EPI == EPI_FC1 || EPI == EPI_FC2) {
        ushort4 u;
        u.x = f2bf(v[0]); u.y = f2bf(v[1]); u.z = f2bf(v[2]); u.w = f2bf(v[3]);
        int pos = (m_base >> 3) ^ (t & 7);
        *(ushort4*)(out + (size_t)t * M + (pos << 3) + (m_base & 7)) = u;
      } else {
        int z = t >> 10, y = (t >> 5) & 31, xx = t & 31;
        int win = ((z >> 3) << 4) + ((y >> 3) << 2) + (xx >> 3);
        int n = ((z & 7) << 6) + ((y & 7) << 3) + (xx & 7);
        if (EPI == EPI_Q) {
          int head = m_base >> 5, dim = m_base & 31;
          ushort4 u;
          u.x = f2bf(v[0]); u.y = f2bf(v[1]); u.z = f2bf(v[2]); u.w = f2bf(v[3]);
          *(ushort4*)(out + ((size_t)(win * 6 + head) * 512 + n) * 32 + dim) = u;
        } else if (m_base < 192) {  // K: padded [512][36] layout
          int head = m_base >> 5, dim = m_base & 31;
          ushort4 u;
          u.x = f2bf(v[0]); u.y = f2bf(v[1]); u.z = f2bf(v[2]); u.w = f2bf(v[3]);
          *(ushort4*)(out + ((size_t)(win * 6 + head) * 512 + n) * 36 + dim) = u;
        } else {
          int vb = m_base - 192;
          int head = vb >> 5, dimb = vb & 31;
#pragma unroll
          for (int r = 0; r < 4; ++r) {
            int dimr = dimb + r;
            out2[((size_t)(win * 6 + head) * 32 + dimr) * 512 +
                 (((n >> 3) ^ (dimr & 7)) << 3) + (n & 7)] = f2bf(v[r]);
          }
        }
      }
    }
  }
}

// ---------------------------------------------------------------------------
// Windowed cosine attention. Grid (zq*6+head = 12, win = 64) = 768 blocks
// (3/CU co-resident; LDS 36.9KB). K pre-normalized padded [512][36] ->
// linear global_load_lds staging. Q pre-normalized+scaled -> raw loads.
// V from global (L1/L2-resident, 8x reuse). Streaming softmax, ones-MFMA
// row sums, cvtpk+permlane P, unroll-4 + setprio around MFMA clusters.
// ---------------------------------------------------------------------------
__global__ __launch_bounds__(256) void k_attn(const u16* __restrict__ Qw,
    const u16* __restrict__ Kw, const u16* __restrict__ Vw,
    u16* __restrict__ Amat) {
  __shared__ u16 Kn[512 * 36];
  int tid = threadIdx.x, lane = tid & 63, wid = tid >> 6;
  int g = lane >> 4, c = lane & 15;
  int zq = blockIdx.x / 6, head = blockIdx.x % 6, win = blockIdx.y;
  const u16* Kg = Kw + (size_t)(win * 6 + head) * 18432;
  const u16* Vg = Vw + (size_t)(win * 6 + head) * 16384;
  const u16* Qg = Qw + (size_t)(win * 6 + head) * 16384;
  for (int i = tid; i < 2304; i += 256)
    gld_lds16(Kg + (size_t)i * 8, Kn + (size_t)i * 8);
  __syncthreads();

  int wz = win >> 4, wy = (win >> 2) & 3, wx = win & 3;
  u32x4 onepk;
  onepk[0] = 0x3F803F80u; onepk[1] = 0x3F803F80u;
  onepk[2] = 0x3F803F80u; onepk[3] = 0x3F803F80u;
  short8 ONES = __builtin_bit_cast(short8, onepk);

  for (int qp = 0; qp < 2; ++qp) {
    int q0A = zq * 256 + wid * 64 + qp * 32;
    int q0B = q0A + 16;
    short8 qfA = *(const short8*)(Qg + (size_t)(q0A + c) * 32 + g * 8);
    short8 qfB = *(const short8*)(Qg + (size_t)(q0B + c) * 32 + g * 8);

    f32x4 o0A = {0.f, 0.f, 0.f, 0.f}, o1A = {0.f, 0.f, 0.f, 0.f};
    f32x4 o2A = {0.f, 0.f, 0.f, 0.f};
    f32x4 o0B = {0.f, 0.f, 0.f, 0.f}, o1B = {0.f, 0.f, 0.f, 0.f};
    f32x4 o2B = {0.f, 0.f, 0.f, 0.f};
#pragma unroll 4
    for (int cc = 0; cc < 16; ++cc) {
      short8 kf0 = *(const short8*)(Kn + (size_t)(cc * 32 + c) * 36 + g * 8);
      short8 kf1 = *(const short8*)(Kn + (size_t)(cc * 32 + 16 + c) * 36 + g * 8);
      int chpos = ((cc * 4 + g) ^ (c & 7)) << 3;
      short8 vf0 = *(const short8*)(Vg + (size_t)c * 512 + chpos);
      short8 vf1 = *(const short8*)(Vg + (size_t)(16 + c) * 512 + chpos);
      __builtin_amdgcn_s_setprio(1);
      f32x4 s0A = __builtin_amdgcn_mfma_f32_16x16x32_bf16(
          kf0, qfA, f32x4{0.f, 0.f, 0.f, 0.f}, 0, 0, 0);
      f32x4 s1A = __builtin_amdgcn_mfma_f32_16x16x32_bf16(
          kf1, qfA, f32x4{0.f, 0.f, 0.f, 0.f}, 0, 0, 0);
      f32x4 s0B = __builtin_amdgcn_mfma_f32_16x16x32_bf16(
          kf0, qfB, f32x4{0.f, 0.f, 0.f, 0.f}, 0, 0, 0);
      f32x4 s1B = __builtin_amdgcn_mfma_f32_16x16x32_bf16(
          kf1, qfB, f32x4{0.f, 0.f, 0.f, 0.f}, 0, 0, 0);
      __builtin_amdgcn_s_setprio(0);
      f32x4 p0A, p1A, p0B, p1B;
#pragma unroll
      for (int r = 0; r < 4; ++r) {
        p0A[r] = __builtin_amdgcn_exp2f(s0A[r]);
        p1A[r] = __builtin_amdgcn_exp2f(s1A[r]);
        p0B[r] = __builtin_amdgcn_exp2f(s0B[r]);
        p1B[r] = __builtin_amdgcn_exp2f(s1B[r]);
      }
      u32 waA = cvtpk(p0A[0], p0A[1]), wbA = cvtpk(p0A[2], p0A[3]);
      u32 wcA = cvtpk(p1A[0], p1A[1]), wdA = cvtpk(p1A[2], p1A[3]);
      plswap(waA, wcA);
      plswap(wbA, wdA);
      u32 waB = cvtpk(p0B[0], p0B[1]), wbB = cvtpk(p0B[2], p0B[3]);
      u32 wcB = cvtpk(p1B[0], p1B[1]), wdB = cvtpk(p1B[2], p1B[3]);
      plswap(waB, wcB);
      plswap(wbB, wdB);
      u32x4 pwA, pwB;
      pwA[0] = waA; pwA[1] = wbA; pwA[2] = wcA; pwA[3] = wdA;
      pwB[0] = waB; pwB[1] = wbB; pwB[2] = wcB; pwB[3] = wdB;
      short8 pfA = __builtin_bit_cast(short8, pwA);
      short8 pfB = __builtin_bit_cast(short8, pwB);
      __builtin_amdgcn_s_setprio(1);
      o0A = __builtin_amdgcn_mfma_f32_16x16x32_bf16(pfA, vf0, o0A, 0, 0, 0);
      o1A = __builtin_amdgcn_mfma_f32_16x16x32_bf16(pfA, vf1, o1A, 0, 0, 0);
      o2A = __builtin_amdgcn_mfma_f32_16x16x32_bf16(pfA, ONES, o2A, 0, 0, 0);
      o0B = __builtin_amdgcn_mfma_f32_16x16x32_bf16(pfB, vf0, o0B, 0, 0, 0);
      o1B = __builtin_amdgcn_mfma_f32_16x16x32_bf16(pfB, vf1, o1B, 0, 0, 0);
      o2B = __builtin_amdgcn_mfma_f32_16x16x32_bf16(pfB, ONES, o2B, 0, 0, 0);
      __builtin_amdgcn_s_setprio(0);
    }

#pragma unroll
    for (int half = 0; half < 2; ++half) {
      f32x4 oo0 = half ? o0B : o0A;
      f32x4 oo1 = half ? o1B : o1A;
      f32x4 osum = half ? o2B : o2A;
      int q0 = half ? q0B : q0A;
      int cg0 = head * 32 + c;
      int cg1 = cg0 + 16;
#pragma unroll
      for (int r = 0; r < 4; ++r) {
        float rs = 1.0f / osum[r];
        int n = q0 + 4 * g + r;
        int dz = n >> 6, dy = (n >> 3) & 7, dx = n & 7;
        int t = (wz * 8 + dz) * 1024 + (wy * 8 + dy) * 32 + wx * 8 + dx;
        Amat[(size_t)t * 192 + (((cg0 >> 3) ^ (t & 7)) << 3) + (cg0 & 7)] =
            f2bf(oo0[r] * rs);
        Amat[(size_t)t * 192 + (((cg1 >> 3) ^ (t & 7)) << 3) + (cg1 & 7)] =
            f2bf(oo1[r] * rs);
      }
    }
  }
}

// ---------------------------------------------------------------------------
// Fused proj-GEMM + residual + LayerNorm, hybrid form: W fragments in
// registers (one-time L2-hot read), Amat staged via coalesced
// global_load_lds. Tile: all 192 channels x 64 tokens, 4 waves x 48 rows.
// ---------------------------------------------------------------------------
__global__ __launch_bounds__(256) void k_proj_ln(const u16* __restrict__ W,
    const u16* __restrict__ B, const float* __restrict__ bias,
    const float* __restrict__ x, const float* __restrict__ gg,
    const float* __restrict__ bb, float* __restrict__ out) {
  __shared__ u16 lB[64 * 64];         // 8KB
  __shared__ float red[2][4][64];     // 2KB
  int tid = threadIdx.x;
  int lane = tid & 63, wid = tid >> 6;
  int g = lane >> 4, c = lane & 15;
  int t0 = blockIdx.x * 64;

  short8 af[3][6];
#pragma unroll
  for (int mt = 0; mt < 3; ++mt) {
    const u16* wr = W + (size_t)(wid * 48 + mt * 16 + c) * 192;
#pragma unroll
    for (int kc = 0; kc < 6; ++kc) {
      int l = kc * 4 + g;
      int pos = (l & ~7) | ((l ^ c) & 7);
      af[mt][kc] = *(const short8*)(wr + pos * 8);
    }
  }

  f32x4 acc[3][4];
#pragma unroll
  for (int i = 0; i < 3; ++i)
#pragma unroll
    for (int j = 0; j < 4; ++j) acc[i][j] = f32x4{0.f, 0.f, 0.f, 0.f};

  for (int s = 0; s < 3; ++s) {
    __syncthreads();
#pragma unroll
    for (int i0 = 0; i0 < 512; i0 += 256) {
      int ii = i0 + tid;
      int r = ii >> 3, ch = ii & 7;
      gld_lds16(B + (size_t)(t0 + r) * 192 + s * 64 + ch * 8,
                lB + (size_t)(ii & ~63) * 8);
    }
    __syncthreads();
#pragma unroll
    for (int kc2 = 0; kc2 < 2; ++kc2) {
      short8 bfr[4];
#pragma unroll
      for (int tt = 0; tt < 4; ++tt) {
        int r = tt * 16 + c;
        bfr[tt] = *(const short8*)(lB + r * 64 + (((kc2 * 4 + g) ^ (r & 7)) << 3));
      }
#pragma unroll
      for (int mt = 0; mt < 3; ++mt)
#pragma unroll
        for (int tt = 0; tt < 4; ++tt)
          acc[mt][tt] = __builtin_amdgcn_mfma_f32_16x16x32_bf16(
              af[mt][s * 2 + kc2], bfr[tt], acc[mt][tt], 0, 0, 0);
    }
  }

  float br[3][4];
#pragma unroll
  for (int mt = 0; mt < 3; ++mt) {
    float4 b4 = *(const float4*)(bias + wid * 48 + mt * 16 + 4 * g);
    br[mt][0] = b4.x; br[mt][1] = b4.y; br[mt][2] = b4.z; br[mt][3] = b4.w;
  }
  float s1[4], s2[4];
#pragma unroll
  for (int tt = 0; tt < 4; ++tt) {
    s1[tt] = 0.f; s2[tt] = 0.f;
#pragma unroll
    for (int mt = 0; mt < 3; ++mt)
#pragma unroll
      for (int r = 0; r < 4; ++r) {
        float v = acc[mt][tt][r] + br[mt][r];
        s1[tt] += v;
        s2[tt] += v * v;
      }
    s1[tt] += __shfl_xor(s1[tt], 16); s1[tt] += __shfl_xor(s1[tt], 32);
    s2[tt] += __shfl_xor(s2[tt], 16); s2[tt] += __shfl_xor(s2[tt], 32);
  }
  if (lane < 16) {
#pragma unroll
    for (int tt = 0; tt < 4; ++tt) {
      red[0][wid][tt * 16 + lane] = s1[tt];
      red[1][wid][tt * 16 + lane] = s2[tt];
    }
  }
  __syncthreads();
  float mean[4], rstd[4];
#pragma unroll
  for (int tt = 0; tt < 4; ++tt) {
    int tl = tt * 16 + c;
    float S1 = (red[0][0][tl] + red[0][1][tl]) + (red[0][2][tl] + red[0][3][tl]);
    float S2 = (red[1][0][tl] + red[1][1][tl]) + (red[1][2][tl] + red[1][3][tl]);
    float m = S1 * (1.0f / 192.0f);
    float var = S2 * (1.0f / 192.0f) - m * m;
    mean[tt] = m;
    rstd[tt] = rsqrtf(var + 1e-5f);
  }
#pragma unroll
  for (int mt = 0; mt < 3; ++mt) {
    int m_base = wid * 48 + mt * 16 + 4 * g;
#pragma unroll
    for (int r = 0; r < 4; ++r) {
      int ch = m_base + r;
      float ga = gg[ch], ba = bb[ch];
      const float* xp = x + (size_t)ch * T_TOT + t0;
      float* op = out + (size_t)ch * T_TOT + t0;
#pragma unroll
      for (int tt = 0; tt < 4; ++tt) {
        int tl = tt * 16 + c;
        float v = acc[mt][tt][r] + br[mt][r];
        op[tl] = xp[tl] + (v - mean[tt]) * rstd[tt] * ga + ba;
      }
    }
  }
}

// ---------------------------------------------------------------------------
extern "C" void kernel_launch(void* const* d_in, const int* in_sizes, int n_in,
                              void* d_out, int out_size, void* d_ws, size_t ws_size,
                              hipStream_t stream) {
  const float* x      = (const float*)d_in[0];
  const float* prev   = (const float*)d_in[1];
  const float* fc1_w  = (const float*)d_in[2];
  const float* fc1_b  = (const float*)d_in[3];
  const float* fc2_w  = (const float*)d_in[4];
  const float* fc2_b  = (const float*)d_in[5];
  const float* q_w    = (const float*)d_in[6];
  const float* q_b    = (const float*)d_in[7];
  const float* kv_w   = (const float*)d_in[8];
  const float* v_b    = (const float*)d_in[9];
  const float* proj_w = (const float*)d_in[10];
  const float* proj_b = (const float*)d_in[11];
  const float* lsc    = (const float*)d_in[12];
  const float* ln_g   = (const float*)d_in[13];
  const float* ln_b   = (const float*)d_in[14];
  float* out = (float*)d_out;
  char* ws = (char*)d_ws;

  u16* Pt   = (u16*)(ws + 0);          // [32768][256] bf16 swz   (16 MiB)
  u16* Y1t  = (u16*)(ws + 16777216);   // [32768][256]            (16 MiB)
  u16* Zt   = (u16*)(ws + 33554432);   // [32768][192]            (12 MiB)
  u16* Xt   = (u16*)(ws + 46137344);   // [32768][192] (dead after q-GEMM)
  u16* Kwin = (u16*)(ws + 46137344);   // [384][512][36] padded (aliases Xt)
  u16* Vwin = (u16*)(ws + 60293120);   // [64][6][32][512] swz    (12 MiB)
  u16* Wbf  = (u16*)(ws + 72876032);   // 262144 bf16 weights
  u16* Qwin = Pt;    // alias: Pt dead after fc1
  u16* Amat = Y1t;   // alias: Y1t dead after fc2

  k_wconv<<<128, 256, 0, stream>>>(fc1_w, fc2_w, q_w, kv_w, proj_w, Wbf);
  k_transpose<256><<<dim3(4, 512), 256, 0, stream>>>(prev, Pt);
  k_transpose<192><<<dim3(3, 512), 256, 0, stream>>>(x, Xt);
  k_gemm<256, 256, EPI_FC1><<<dim3(256, 4), 256, 0, stream>>>(Wbf, Pt, fc1_b, nullptr, Y1t, nullptr);
  k_gemm<192, 256, EPI_FC2><<<dim3(256, 3), 256, 0, stream>>>(Wbf + 65536, Y1t, fc2_b, nullptr, Zt, nullptr);
  k_gemm<192, 192, EPI_Q><<<dim3(256, 3), 256, 0, stream>>>(Wbf + 114688, Xt, q_b, lsc, Qwin, nullptr);
  k_gemm<384, 192, EPI_KV><<<dim3(256, 6), 256, 0, stream>>>(Wbf + 151552, Zt, v_b, nullptr, Kwin, Vwin);
  k_attn<<<dim3(12, 64), 256, 0, stream>>>(Qwin, Kwin, Vwin, Amat);
  k_proj_ln<<<512, 256, 0, stream>>>(Wbf + 225280, Amat, proj_b, x, ln_g, ln_b, out);
}

// Round 14
// 111.912 us; speedup vs baseline: 1.9716x; 1.1377x over previous
//
#include <hip/hip_runtime.h>
#include <stdint.h>

typedef unsigned short u16;
typedef unsigned int u32;
typedef short short8 __attribute__((ext_vector_type(8)));
typedef float f32x4 __attribute__((ext_vector_type(4)));
typedef u32 u32x4 __attribute__((ext_vector_type(4)));

#define T_TOT 32768

__device__ __forceinline__ u16 f2bf(float f) {
  u32 u = __float_as_uint(f);
  return (u16)((u + 0x7fffu + ((u >> 16) & 1u)) >> 16);
}
__device__ __forceinline__ float bf2f(u16 h) {
  return __uint_as_float(((u32)h) << 16);
}
// HW pack: lo=bf16(a), hi=bf16(b). Plain VALU op -> safe as inline asm.
__device__ __forceinline__ u32 cvtpk(float a, float b) {
  u32 r;
  asm("v_cvt_pk_bf16_f32 %0, %1, %2" : "=v"(r) : "v"(a), "v"(b));
  return r;
}

// Async global->LDS 16B copy (direct-to-LDS, no VGPR round trip).
__device__ __forceinline__ void gld_lds16(const void* g, void* l) {
  __builtin_amdgcn_global_load_lds(
      (const __attribute__((address_space(1))) u32*)g,
      (__attribute__((address_space(3))) u32*)l, 16, 0, 0);
}

// P-redistribution double swap (builtin form -> compiler inserts the
// DPP cross-lane wait states; raw-asm version raced).
__device__ __forceinline__ void plswap(u32& a, u32& b) {
#if __has_builtin(__builtin_amdgcn_permlane32_swap) && \
    __has_builtin(__builtin_amdgcn_permlane16_swap)
  typedef u32 u32x2v __attribute__((ext_vector_type(2)));
  u32x2v r = __builtin_amdgcn_permlane32_swap(a, b, false, false);
  u32x2v w = __builtin_amdgcn_permlane16_swap(r[0], r[1], false, false);
  a = w[0]; b = w[1];
#else
  asm volatile(
      "s_nop 2\n\t"
      "v_permlane32_swap_b32 %0, %1\n\t"
      "s_nop 2\n\t"
      "v_permlane16_swap_b32 %0, %1\n\t"
      "s_nop 2"
      : "+v"(a), "+v"(b));
#endif
}

// ---------------------------------------------------------------------------
// Merged prep: weight-convert + both fp32->bf16 transposes in ONE launch
// (they are mutually independent; block-uniform branch by blockIdx range).
// ---------------------------------------------------------------------------
__global__ __launch_bounds__(256) void k_prep(
    const float* __restrict__ fc1, const float* __restrict__ fc2,
    const float* __restrict__ qw, const float* __restrict__ kvw,
    const float* __restrict__ pw, u16* __restrict__ wout,
    const float* __restrict__ prev, u16* __restrict__ Pt,
    const float* __restrict__ x, u16* __restrict__ Xt) {
  __shared__ u16 sT[64][72];
  int b = blockIdx.x;
  int tid = threadIdx.x;
  if (b < 128) {
    // ---- weight convert: fp32 -> bf16, 16B-chunk XOR swizzle by row ----
    int idx = b * 256 + tid;
    const float* src; int K; int rel; u16* dst;
    if (idx < 8192)       { src = fc1; K = 256; rel = idx;         dst = wout; }
    else if (idx < 14336) { src = fc2; K = 256; rel = idx - 8192;  dst = wout + 65536; }
    else if (idx < 18944) { src = qw;  K = 192; rel = idx - 14336; dst = wout + 114688; }
    else if (idx < 28160) { src = kvw; K = 192; rel = idx - 18944; dst = wout + 151552; }
    else                  { src = pw;  K = 192; rel = idx - 28160; dst = wout + 225280; }
    int nch = K >> 3;
    int m = rel / nch, ch = rel % nch;
    const float* sp = src + (size_t)m * K + ch * 8;
    int pos = (ch & ~7) | ((ch ^ m) & 7);
    u16* dp = dst + (size_t)m * K + pos * 8;
    ushort4 u0, u1;
    u0.x = f2bf(sp[0]); u0.y = f2bf(sp[1]); u0.z = f2bf(sp[2]); u0.w = f2bf(sp[3]);
    u1.x = f2bf(sp[4]); u1.y = f2bf(sp[5]); u1.z = f2bf(sp[6]); u1.w = f2bf(sp[7]);
    *(ushort4*)(dp) = u0;
    *(ushort4*)(dp + 4) = u1;
    return;
  }
  // ---- transpose: src fp32 [C][32768] -> dst bf16 [32768][C] swizzled ----
  const float* src;
  u16* dst;
  int C, c0, t0;
  if (b < 2176) {
    int bb = b - 128;
    src = prev; dst = Pt; C = 256;
    c0 = (bb & 3) * 64; t0 = (bb >> 2) * 64;
  } else {
    int bb = b - 2176;
    src = x; dst = Xt; C = 192;
    c0 = (bb % 3) * 64; t0 = (bb / 3) * 64;
  }
  for (int i = tid; i < 1024; i += 256) {
    int row = i >> 4;
    int tb  = (i & 15) * 4;
    const float* sp = src + (size_t)(c0 + row) * T_TOT + t0 + tb;
    float4 v = *(const float4*)sp;
    ushort4 u;
    u.x = f2bf(v.x); u.y = f2bf(v.y); u.z = f2bf(v.z); u.w = f2bf(v.w);
    *(ushort4*)(&sT[row][tb]) = u;
  }
  __syncthreads();
  int tl = tid & 63;
  int jb = tid >> 6;
  for (int p = 0; p < 2; ++p) {
    int j = jb + 4 * p;
    int t = t0 + tl;
    u16 e[8];
#pragma unroll
    for (int e8 = 0; e8 < 8; ++e8) e[e8] = sT[j * 8 + e8][tl];
    int pos = (c0 >> 3) + (j ^ (t & 7));
    uint4 o;
    o.x = (u32)e[0] | ((u32)e[1] << 16);
    o.y = (u32)e[2] | ((u32)e[3] << 16);
    o.z = (u32)e[4] | ((u32)e[5] << 16);
    o.w = (u32)e[6] | ((u32)e[7] << 16);
    *(uint4*)(dst + (size_t)t * C + pos * 8) = o;
  }
}

// ---------------------------------------------------------------------------
// GEMM (R11 form): out(M x 32768) = W(MxK) * Bt^T. 64m x 128t tile, 4 waves,
// global_load_lds staging for BOTH operands, swizzle on the ds_read side.
// ---------------------------------------------------------------------------
enum { EPI_FC1 = 0, EPI_FC2 = 1 };

template<int M, int K, int EPI>
__global__ __launch_bounds__(256) void k_gemm(const u16* __restrict__ W,
    const u16* __restrict__ B, const float* __restrict__ bias,
    u16* __restrict__ out) {
  __shared__ u16 lW[64 * 64];
  __shared__ u16 lB[128 * 64];
  int tid = threadIdx.x;
  int lane = tid & 63, wid = tid >> 6;
  int g = lane >> 4, c = lane & 15;
  int wm = wid >> 1, wt = wid & 1;
  int t0 = blockIdx.x * 128, m0 = blockIdx.y * 64;
  f32x4 acc[2][4];
#pragma unroll
  for (int i = 0; i < 2; ++i)
#pragma unroll
    for (int j = 0; j < 4; ++j) acc[i][j] = f32x4{0.f, 0.f, 0.f, 0.f};

  for (int s = 0; s < K / 64; ++s) {
    __syncthreads();
#pragma unroll
    for (int i0 = 0; i0 < 512; i0 += 256) {
      int i = i0 + tid;
      int r = i >> 3, ch = i & 7;
      gld_lds16(W + (size_t)(m0 + r) * K + s * 64 + ch * 8,
                lW + (size_t)(i & ~63) * 8);
    }
#pragma unroll
    for (int i0 = 0; i0 < 1024; i0 += 256) {
      int i = i0 + tid;
      int r = i >> 3, ch = i & 7;
      gld_lds16(B + (size_t)(t0 + r) * K + s * 64 + ch * 8,
                lB + (size_t)(i & ~63) * 8);
    }
    __syncthreads();
#pragma unroll
    for (int kc = 0; kc < 2; ++kc) {
      short8 af[2], bfr[4];
#pragma unroll
      for (int mt = 0; mt < 2; ++mt) {
        int r = wm * 32 + mt * 16 + c;
        af[mt] = *(const short8*)(lW + r * 64 + (((kc * 4 + g) ^ (r & 7)) << 3));
      }
#pragma unroll
      for (int tt = 0; tt < 4; ++tt) {
        int r = wt * 64 + tt * 16 + c;
        bfr[tt] = *(const short8*)(lB + r * 64 + (((kc * 4 + g) ^ (r & 7)) << 3));
      }
#pragma unroll
      for (int mt = 0; mt < 2; ++mt)
#pragma unroll
        for (int tt = 0; tt < 4; ++tt)
          acc[mt][tt] = __builtin_amdgcn_mfma_f32_16x16x32_bf16(
              af[mt], bfr[tt], acc[mt][tt], 0, 0, 0);
    }
  }

#pragma unroll
  for (int mt = 0; mt < 2; ++mt) {
    int m_base = m0 + wm * 32 + mt * 16 + 4 * g;
    float4 b4 = *(const float4*)(bias + m_base);
    float br[4] = {b4.x, b4.y, b4.z, b4.w};
#pragma unroll
    for (int tt = 0; tt < 4; ++tt) {
      int t = t0 + wt * 64 + tt * 16 + c;
      float v[4];
#pragma unroll
      for (int r = 0; r < 4; ++r) v[r] = acc[mt][tt][r] + br[r];
      if constexpr (EPI == EPI_FC1) {
#pragma unroll
        for (int r = 0; r < 4; ++r)
          v[r] = 0.5f * v[r] * (1.0f + erff(v[r] * 0.70710678118654752f));
      }
      ushort4 u;
      u.x = f2bf(v[0]); u.y = f2bf(v[1]); u.z = f2bf(v[2]); u.w = f2bf(v[3]);
      int pos = (m_base >> 3) ^ (t & 7);
      *(ushort4*)(out + (size_t)t * M + (pos << 3) + (m_base & 7)) = u;
    }
  }
}

// ---------------------------------------------------------------------------
// Merged Q + KV projection GEMM (both depend only on prep/fc2; one launch).
// blocks [0,768): Q path; [768,2304): KV path. Same K=192 inner loop.
// Epilogues fold cosine-norm (Q adds exp(min(ls,ln100))*log2e); K written in
// attn's padded [512][36] layout; V dim-major chunk-swizzled.
// ---------------------------------------------------------------------------
__global__ __launch_bounds__(256) void k_qkv(const u16* __restrict__ Wq,
    const u16* __restrict__ Wkv, const u16* __restrict__ Xt,
    const u16* __restrict__ Zt, const float* __restrict__ q_b,
    const float* __restrict__ v_b, const float* __restrict__ ls,
    u16* __restrict__ Qwin, u16* __restrict__ Kwin, u16* __restrict__ Vwin) {
  __shared__ u16 lW[64 * 64];
  __shared__ u16 lB[128 * 64];
  int b = blockIdx.x;
  bool isQ = b < 768;
  int bb = isQ ? b : b - 768;
  int t0 = (bb & 255) * 128, m0 = (bb >> 8) * 64;
  const u16* W = isQ ? Wq : Wkv;
  const u16* B = isQ ? Xt : Zt;
  int tid = threadIdx.x;
  int lane = tid & 63, wid = tid >> 6;
  int g = lane >> 4, c = lane & 15;
  int wm = wid >> 1, wt = wid & 1;
  f32x4 acc[2][4];
#pragma unroll
  for (int i = 0; i < 2; ++i)
#pragma unroll
    for (int j = 0; j < 4; ++j) acc[i][j] = f32x4{0.f, 0.f, 0.f, 0.f};

  for (int s = 0; s < 3; ++s) {
    __syncthreads();
#pragma unroll
    for (int i0 = 0; i0 < 512; i0 += 256) {
      int i = i0 + tid;
      int r = i >> 3, ch = i & 7;
      gld_lds16(W + (size_t)(m0 + r) * 192 + s * 64 + ch * 8,
                lW + (size_t)(i & ~63) * 8);
    }
#pragma unroll
    for (int i0 = 0; i0 < 1024; i0 += 256) {
      int i = i0 + tid;
      int r = i >> 3, ch = i & 7;
      gld_lds16(B + (size_t)(t0 + r) * 192 + s * 64 + ch * 8,
                lB + (size_t)(i & ~63) * 8);
    }
    __syncthreads();
#pragma unroll
    for (int kc = 0; kc < 2; ++kc) {
      short8 af[2], bfr[4];
#pragma unroll
      for (int mt = 0; mt < 2; ++mt) {
        int r = wm * 32 + mt * 16 + c;
        af[mt] = *(const short8*)(lW + r * 64 + (((kc * 4 + g) ^ (r & 7)) << 3));
      }
#pragma unroll
      for (int tt = 0; tt < 4; ++tt) {
        int r = wt * 64 + tt * 16 + c;
        bfr[tt] = *(const short8*)(lB + r * 64 + (((kc * 4 + g) ^ (r & 7)) << 3));
      }
#pragma unroll
      for (int mt = 0; mt < 2; ++mt)
#pragma unroll
        for (int tt = 0; tt < 4; ++tt)
          acc[mt][tt] = __builtin_amdgcn_mfma_f32_16x16x32_bf16(
              af[mt], bfr[tt], acc[mt][tt], 0, 0, 0);
    }
  }

  // bias
  float vv[2][4][4];
#pragma unroll
  for (int mt = 0; mt < 2; ++mt) {
    int m_base = m0 + wm * 32 + mt * 16 + 4 * g;
    float br[4];
    if (isQ) {
      float4 b4 = *(const float4*)(q_b + m_base);
      br[0] = b4.x; br[1] = b4.y; br[2] = b4.z; br[3] = b4.w;
    } else if (m_base >= 192) {
      float4 b4 = *(const float4*)(v_b + (m_base - 192));
      br[0] = b4.x; br[1] = b4.y; br[2] = b4.z; br[3] = b4.w;
    } else {
      br[0] = br[1] = br[2] = br[3] = 0.f;
    }
#pragma unroll
    for (int tt = 0; tt < 4; ++tt)
#pragma unroll
      for (int r = 0; r < 4; ++r) vv[mt][tt][r] = acc[mt][tt][r] + br[r];
  }

  // cosine-normalize Q rows (with scale) and K rows
  if (isQ || m0 < 192) {
    float sc = 1.0f;
    if (isQ) {
      int headq = (m0 + wm * 32) >> 5;
      sc = __expf(fminf(ls[headq], 4.6051701859880914f)) * 1.4426950408889634f;
    }
#pragma unroll
    for (int tt = 0; tt < 4; ++tt) {
      float ss = 0.f;
#pragma unroll
      for (int mt = 0; mt < 2; ++mt)
#pragma unroll
        for (int r = 0; r < 4; ++r) ss += vv[mt][tt][r] * vv[mt][tt][r];
      ss += __shfl_xor(ss, 16);
      ss += __shfl_xor(ss, 32);
      float rn = sc / fmaxf(sqrtf(ss), 1e-12f);
#pragma unroll
      for (int mt = 0; mt < 2; ++mt)
#pragma unroll
        for (int r = 0; r < 4; ++r) vv[mt][tt][r] *= rn;
    }
  }

#pragma unroll
  for (int mt = 0; mt < 2; ++mt) {
    int m_base = m0 + wm * 32 + mt * 16 + 4 * g;
#pragma unroll
    for (int tt = 0; tt < 4; ++tt) {
      int t = t0 + wt * 64 + tt * 16 + c;
      int z = t >> 10, y = (t >> 5) & 31, xx = t & 31;
      int win = ((z >> 3) << 4) + ((y >> 3) << 2) + (xx >> 3);
      int n = ((z & 7) << 6) + ((y & 7) << 3) + (xx & 7);
      float v[4];
#pragma unroll
      for (int r = 0; r < 4; ++r) v[r] = vv[mt][tt][r];
      if (isQ) {
        int head = m_base >> 5, dim = m_base & 31;
        ushort4 u;
        u.x = f2bf(v[0]); u.y = f2bf(v[1]); u.z = f2bf(v[2]); u.w = f2bf(v[3]);
        *(ushort4*)(Qwin + ((size_t)(win * 6 + head) * 512 + n) * 32 + dim) = u;
      } else if (m_base < 192) {  // K: padded [512][36] layout
        int head = m_base >> 5, dim = m_base & 31;
        ushort4 u;
        u.x = f2bf(v[0]); u.y = f2bf(v[1]); u.z = f2bf(v[2]); u.w = f2bf(v[3]);
        *(ushort4*)(Kwin + ((size_t)(win * 6 + head) * 512 + n) * 36 + dim) = u;
      } else {
        int vb = m_base - 192;
        int head = vb >> 5, dimb = vb & 31;
#pragma unroll
        for (int r = 0; r < 4; ++r) {
          int dimr = dimb + r;
          Vwin[((size_t)(win * 6 + head) * 32 + dimr) * 512 +
               (((n >> 3) ^ (dimr & 7)) << 3) + (n & 7)] = f2bf(v[r]);
        }
      }
    }
  }
}

// ---------------------------------------------------------------------------
// Windowed cosine attention (R11 form, unchanged).
// ---------------------------------------------------------------------------
__global__ __launch_bounds__(256) void k_attn(const u16* __restrict__ Qw,
    const u16* __restrict__ Kw, const u16* __restrict__ Vw,
    u16* __restrict__ Amat) {
  __shared__ u16 Kn[512 * 36];
  int tid = threadIdx.x, lane = tid & 63, wid = tid >> 6;
  int g = lane >> 4, c = lane & 15;
  int zq = blockIdx.x / 6, head = blockIdx.x % 6, win = blockIdx.y;
  const u16* Kg = Kw + (size_t)(win * 6 + head) * 18432;
  const u16* Vg = Vw + (size_t)(win * 6 + head) * 16384;
  const u16* Qg = Qw + (size_t)(win * 6 + head) * 16384;
  for (int i = tid; i < 2304; i += 256)
    gld_lds16(Kg + (size_t)i * 8, Kn + (size_t)i * 8);
  __syncthreads();

  int wz = win >> 4, wy = (win >> 2) & 3, wx = win & 3;
  u32x4 onepk;
  onepk[0] = 0x3F803F80u; onepk[1] = 0x3F803F80u;
  onepk[2] = 0x3F803F80u; onepk[3] = 0x3F803F80u;
  short8 ONES = __builtin_bit_cast(short8, onepk);

  for (int qp = 0; qp < 2; ++qp) {
    int q0A = zq * 256 + wid * 64 + qp * 32;
    int q0B = q0A + 16;
    short8 qfA = *(const short8*)(Qg + (size_t)(q0A + c) * 32 + g * 8);
    short8 qfB = *(const short8*)(Qg + (size_t)(q0B + c) * 32 + g * 8);

    f32x4 o0A = {0.f, 0.f, 0.f, 0.f}, o1A = {0.f, 0.f, 0.f, 0.f};
    f32x4 o2A = {0.f, 0.f, 0.f, 0.f};
    f32x4 o0B = {0.f, 0.f, 0.f, 0.f}, o1B = {0.f, 0.f, 0.f, 0.f};
    f32x4 o2B = {0.f, 0.f, 0.f, 0.f};
#pragma unroll 4
    for (int cc = 0; cc < 16; ++cc) {
      short8 kf0 = *(const short8*)(Kn + (size_t)(cc * 32 + c) * 36 + g * 8);
      short8 kf1 = *(const short8*)(Kn + (size_t)(cc * 32 + 16 + c) * 36 + g * 8);
      int chpos = ((cc * 4 + g) ^ (c & 7)) << 3;
      short8 vf0 = *(const short8*)(Vg + (size_t)c * 512 + chpos);
      short8 vf1 = *(const short8*)(Vg + (size_t)(16 + c) * 512 + chpos);
      __builtin_amdgcn_s_setprio(1);
      f32x4 s0A = __builtin_amdgcn_mfma_f32_16x16x32_bf16(
          kf0, qfA, f32x4{0.f, 0.f, 0.f, 0.f}, 0, 0, 0);
      f32x4 s1A = __builtin_amdgcn_mfma_f32_16x16x32_bf16(
          kf1, qfA, f32x4{0.f, 0.f, 0.f, 0.f}, 0, 0, 0);
      f32x4 s0B = __builtin_amdgcn_mfma_f32_16x16x32_bf16(
          kf0, qfB, f32x4{0.f, 0.f, 0.f, 0.f}, 0, 0, 0);
      f32x4 s1B = __builtin_amdgcn_mfma_f32_16x16x32_bf16(
          kf1, qfB, f32x4{0.f, 0.f, 0.f, 0.f}, 0, 0, 0);
      __builtin_amdgcn_s_setprio(0);
      f32x4 p0A, p1A, p0B, p1B;
#pragma unroll
      for (int r = 0; r < 4; ++r) {
        p0A[r] = __builtin_amdgcn_exp2f(s0A[r]);
        p1A[r] = __builtin_amdgcn_exp2f(s1A[r]);
        p0B[r] = __builtin_amdgcn_exp2f(s0B[r]);
        p1B[r] = __builtin_amdgcn_exp2f(s1B[r]);
      }
      u32 waA = cvtpk(p0A[0], p0A[1]), wbA = cvtpk(p0A[2], p0A[3]);
      u32 wcA = cvtpk(p1A[0], p1A[1]), wdA = cvtpk(p1A[2], p1A[3]);
      plswap(waA, wcA);
      plswap(wbA, wdA);
      u32 waB = cvtpk(p0B[0], p0B[1]), wbB = cvtpk(p0B[2], p0B[3]);
      u32 wcB = cvtpk(p1B[0], p1B[1]), wdB = cvtpk(p1B[2], p1B[3]);
      plswap(waB, wcB);
      plswap(wbB, wdB);
      u32x4 pwA, pwB;
      pwA[0] = waA; pwA[1] = wbA; pwA[2] = wcA; pwA[3] = wdA;
      pwB[0] = waB; pwB[1] = wbB; pwB[2] = wcB; pwB[3] = wdB;
      short8 pfA = __builtin_bit_cast(short8, pwA);
      short8 pfB = __builtin_bit_cast(short8, pwB);
      __builtin_amdgcn_s_setprio(1);
      o0A = __builtin_amdgcn_mfma_f32_16x16x32_bf16(pfA, vf0, o0A, 0, 0, 0);
      o1A = __builtin_amdgcn_mfma_f32_16x16x32_bf16(pfA, vf1, o1A, 0, 0, 0);
      o2A = __builtin_amdgcn_mfma_f32_16x16x32_bf16(pfA, ONES, o2A, 0, 0, 0);
      o0B = __builtin_amdgcn_mfma_f32_16x16x32_bf16(pfB, vf0, o0B, 0, 0, 0);
      o1B = __builtin_amdgcn_mfma_f32_16x16x32_bf16(pfB, vf1, o1B, 0, 0, 0);
      o2B = __builtin_amdgcn_mfma_f32_16x16x32_bf16(pfB, ONES, o2B, 0, 0, 0);
      __builtin_amdgcn_s_setprio(0);
    }

#pragma unroll
    for (int half = 0; half < 2; ++half) {
      f32x4 oo0 = half ? o0B : o0A;
      f32x4 oo1 = half ? o1B : o1A;
      f32x4 osum = half ? o2B : o2A;
      int q0 = half ? q0B : q0A;
      int cg0 = head * 32 + c;
      int cg1 = cg0 + 16;
#pragma unroll
      for (int r = 0; r < 4; ++r) {
        float rs = 1.0f / osum[r];
        int n = q0 + 4 * g + r;
        int dz = n >> 6, dy = (n >> 3) & 7, dx = n & 7;
        int t = (wz * 8 + dz) * 1024 + (wy * 8 + dy) * 32 + wx * 8 + dx;
        Amat[(size_t)t * 192 + (((cg0 >> 3) ^ (t & 7)) << 3) + (cg0 & 7)] =
            f2bf(oo0[r] * rs);
        Amat[(size_t)t * 192 + (((cg1 >> 3) ^ (t & 7)) << 3) + (cg1 & 7)] =
            f2bf(oo1[r] * rs);
      }
    }
  }
}

// ---------------------------------------------------------------------------
// Fused proj-GEMM + residual + LayerNorm (R11 form: both operands via LDS).
// ---------------------------------------------------------------------------
__global__ __launch_bounds__(256) void k_proj_ln(const u16* __restrict__ W,
    const u16* __restrict__ B, const float* __restrict__ bias,
    const float* __restrict__ x, const float* __restrict__ gg,
    const float* __restrict__ bb, float* __restrict__ out) {
  __shared__ u16 lW[192 * 64];        // 24KB
  __shared__ u16 lB[64 * 64];         // 8KB
  __shared__ float red[2][4][64];     // 2KB
  int tid = threadIdx.x;
  int lane = tid & 63, wid = tid >> 6;
  int g = lane >> 4, c = lane & 15;
  int t0 = blockIdx.x * 64;
  f32x4 acc[3][4];
#pragma unroll
  for (int i = 0; i < 3; ++i)
#pragma unroll
    for (int j = 0; j < 4; ++j) acc[i][j] = f32x4{0.f, 0.f, 0.f, 0.f};

  for (int s = 0; s < 3; ++s) {
    __syncthreads();
#pragma unroll
    for (int i0 = 0; i0 < 1536; i0 += 256) {
      int i = i0 + tid;
      int r = i >> 3, ch = i & 7;
      gld_lds16(W + (size_t)r * 192 + s * 64 + ch * 8,
                lW + (size_t)(i & ~63) * 8);
    }
#pragma unroll
    for (int i0 = 0; i0 < 512; i0 += 256) {
      int ii = i0 + tid;
      int r = ii >> 3, ch = ii & 7;
      gld_lds16(B + (size_t)(t0 + r) * 192 + s * 64 + ch * 8,
                lB + (size_t)(ii & ~63) * 8);
    }
    __syncthreads();
#pragma unroll
    for (int kc = 0; kc < 2; ++kc) {
      short8 af[3], bfr[4];
#pragma unroll
      for (int mt = 0; mt < 3; ++mt) {
        int r = wid * 48 + mt * 16 + c;
        af[mt] = *(const short8*)(lW + r * 64 + (((kc * 4 + g) ^ (r & 7)) << 3));
      }
#pragma unroll
      for (int tt = 0; tt < 4; ++tt) {
        int r = tt * 16 + c;
        bfr[tt] = *(const short8*)(lB + r * 64 + (((kc * 4 + g) ^ (r & 7)) << 3));
      }
#pragma unroll
      for (int mt = 0; mt < 3; ++mt)
#pragma unroll
        for (int tt = 0; tt < 4; ++tt)
          acc[mt][tt] = __builtin_amdgcn_mfma_f32_16x16x32_bf16(
              af[mt], bfr[tt], acc[mt][tt], 0, 0, 0);
    }
  }

  float br[3][4];
#pragma unroll
  for (int mt = 0; mt < 3; ++mt) {
    float4 b4 = *(const float4*)(bias + wid * 48 + mt * 16 + 4 * g);
    br[mt][0] = b4.x; br[mt][1] = b4.y; br[mt][2] = b4.z; br[mt][3] = b4.w;
  }
  float s1[4], s2[4];
#pragma unroll
  for (int tt = 0; tt < 4; ++tt) {
    s1[tt] = 0.f; s2[tt] = 0.f;
#pragma unroll
    for (int mt = 0; mt < 3; ++mt)
#pragma unroll
      for (int r = 0; r < 4; ++r) {
        float v = acc[mt][tt][r] + br[mt][r];
        s1[tt] += v;
        s2[tt] += v * v;
      }
    s1[tt] += __shfl_xor(s1[tt], 16); s1[tt] += __shfl_xor(s1[tt], 32);
    s2[tt] += __shfl_xor(s2[tt], 16); s2[tt] += __shfl_xor(s2[tt], 32);
  }
  if (lane < 16) {
#pragma unroll
    for (int tt = 0; tt < 4; ++tt) {
      red[0][wid][tt * 16 + lane] = s1[tt];
      red[1][wid][tt * 16 + lane] = s2[tt];
    }
  }
  __syncthreads();
  float mean[4], rstd[4];
#pragma unroll
  for (int tt = 0; tt < 4; ++tt) {
    int tl = tt * 16 + c;
    float S1 = (red[0][0][tl] + red[0][1][tl]) + (red[0][2][tl] + red[0][3][tl]);
    float S2 = (red[1][0][tl] + red[1][1][tl]) + (red[1][2][tl] + red[1][3][tl]);
    float m = S1 * (1.0f / 192.0f);
    float var = S2 * (1.0f / 192.0f) - m * m;
    mean[tt] = m;
    rstd[tt] = rsqrtf(var + 1e-5f);
  }
#pragma unroll
  for (int mt = 0; mt < 3; ++mt) {
    int m_base = wid * 48 + mt * 16 + 4 * g;
#pragma unroll
    for (int r = 0; r < 4; ++r) {
      int ch = m_base + r;
      float ga = gg[ch], ba = bb[ch];
      const float* xp = x + (size_t)ch * T_TOT + t0;
      float* op = out + (size_t)ch * T_TOT + t0;
#pragma unroll
      for (int tt = 0; tt < 4; ++tt) {
        int tl = tt * 16 + c;
        float v = acc[mt][tt][r] + br[mt][r];
        op[tl] = xp[tl] + (v - mean[tt]) * rstd[tt] * ga + ba;
      }
    }
  }
}

// ---------------------------------------------------------------------------
extern "C" void kernel_launch(void* const* d_in, const int* in_sizes, int n_in,
                              void* d_out, int out_size, void* d_ws, size_t ws_size,
                              hipStream_t stream) {
  const float* x      = (const float*)d_in[0];
  const float* prev   = (const float*)d_in[1];
  const float* fc1_w  = (const float*)d_in[2];
  const float* fc1_b  = (const float*)d_in[3];
  const float* fc2_w  = (const float*)d_in[4];
  const float* fc2_b  = (const float*)d_in[5];
  const float* q_w    = (const float*)d_in[6];
  const float* q_b    = (const float*)d_in[7];
  const float* kv_w   = (const float*)d_in[8];
  const float* v_b    = (const float*)d_in[9];
  const float* proj_w = (const float*)d_in[10];
  const float* proj_b = (const float*)d_in[11];
  const float* lsc    = (const float*)d_in[12];
  const float* ln_g   = (const float*)d_in[13];
  const float* ln_b   = (const float*)d_in[14];
  float* out = (float*)d_out;
  char* ws = (char*)d_ws;

  u16* Pt   = (u16*)(ws + 0);          // [32768][256] bf16 swz   (16 MiB)
  u16* Y1t  = (u16*)(ws + 16777216);   // [32768][256]            (16 MiB)
  u16* Zt   = (u16*)(ws + 33554432);   // [32768][192]            (12 MiB)
  u16* Xt   = (u16*)(ws + 46137344);   // [32768][192]            (12 MiB)
  u16* Vwin = (u16*)(ws + 60293120);   // [64][6][32][512] swz    (12 MiB)
  u16* Wbf  = (u16*)(ws + 72876032);   // 262144 bf16 weights (0.5 MiB)
  u16* Kwin = (u16*)(ws + 73400320);   // [384][512][36] padded (13.5 MiB)
  u16* Qwin = Pt;    // alias: Pt dead after fc1
  u16* Amat = Y1t;   // alias: Y1t dead after fc2

  k_prep<<<3712, 256, 0, stream>>>(fc1_w, fc2_w, q_w, kv_w, proj_w, Wbf,
                                   prev, Pt, x, Xt);
  k_gemm<256, 256, EPI_FC1><<<dim3(256, 4), 256, 0, stream>>>(Wbf, Pt, fc1_b, Y1t);
  k_gemm<192, 256, EPI_FC2><<<dim3(256, 3), 256, 0, stream>>>(Wbf + 65536, Y1t, fc2_b, Zt);
  k_qkv<<<2304, 256, 0, stream>>>(Wbf + 114688, Wbf + 151552, Xt, Zt,
                                  q_b, v_b, lsc, Qwin, Kwin, Vwin);
  k_attn<<<dim3(12, 64), 256, 0, stream>>>(Qwin, Kwin, Vwin, Amat);
  k_proj_ln<<<512, 256, 0, stream>>>(Wbf + 225280, Amat, proj_b, x, ln_g, ln_b, out);
}